// Round 10
// baseline (337.287 us; speedup 1.0000x reference)
//
#include <hip/hip_runtime.h>
#include <math.h>

#define FF 512
#define EE 32
#define RS 40     // LDS row stride in bf16 elements (80 B: 2-way bank alias = free)
#define FCAP 416  // staged-row cap; cnt = 1+Binom(511,0.5), max over fixed inputs ~300
#define NTCAP 26  // FCAP/16

typedef __attribute__((ext_vector_type(8))) short bf16x8;
typedef __attribute__((ext_vector_type(4))) float f32x4;

// sqrt(1/sqrt(32) * log2(e)) — folded into staged FX so MFMA output is the exp2 arg
#define SFOLD 0.5050092f

__device__ __forceinline__ unsigned short f2bf(float x) {
    unsigned int u = __float_as_uint(x);
    return (unsigned short)((u + 0x7fffu + ((u >> 16) & 1u)) >> 16);
}
__device__ __forceinline__ float bf2f(unsigned short h) {
    return __uint_as_float(((unsigned int)h) << 16);
}
__device__ __forceinline__ float esum4(f32x4 d) {
    return (__builtin_amdgcn_exp2f(d[0]) + __builtin_amdgcn_exp2f(d[1])) +
           (__builtin_amdgcn_exp2f(d[2]) + __builtin_amdgcn_exp2f(d[3]));
}
__device__ __forceinline__ float wsum4(f32x4 d, float4 z, float acc) {
    acc = fmaf(__builtin_amdgcn_exp2f(d[0]), z.x, acc);
    acc = fmaf(__builtin_amdgcn_exp2f(d[1]), z.y, acc);
    acc = fmaf(__builtin_amdgcn_exp2f(d[2]), z.z, acc);
    acc = fmaf(__builtin_amdgcn_exp2f(d[3]), z.w, acc);
    return acc;
}

// ---- pass 1: Z column sums. NC owned cols at c0; R trailing cols shared
// across all 8 waves by i-chunk (A-frags reused from the main loop). ----
template <int NC, int R>
__device__ __forceinline__ void pass1_t(const unsigned short* __restrict__ myrow,
                                        float* __restrict__ Zs,
                                        int c0, int nt, int cnt, float pad,
                                        int lane, int wv) {
    bf16x8 bf[NC];
#pragma unroll
    for (int c = 0; c < NC; ++c)
        bf[c] = *(const bf16x8*)(myrow + (size_t)(c0 + c) * 16 * RS);
    bf16x8 bs[R > 0 ? R : 1];
    float sA[R > 0 ? R : 1], sB[R > 0 ? R : 1];
    if (R > 0) {
#pragma unroll
        for (int s = 0; s < R; ++s) {
            bs[s] = *(const bf16x8*)(myrow + (size_t)(nt - R + s) * 16 * RS);
            sA[s] = 0.f; sB[s] = 0.f;
        }
    }
    float zA[NC], zB[NC];
#pragma unroll
    for (int c = 0; c < NC; ++c) { zA[c] = 0.f; zB[c] = 0.f; }
    const int NPf = nt >> 1;
    const int NP = NPf + (nt & 1);
    const int plo = (wv * NP) >> 3, phi = ((wv + 1) * NP) >> 3;
    const unsigned short* ap = myrow;
    for (int p = 0; p < NPf; ++p) {
        bf16x8 a0 = *(const bf16x8*)(ap);
        bf16x8 a1 = *(const bf16x8*)(ap + 16 * RS);
        ap += 32 * RS;
#pragma unroll
        for (int c = 0; c < NC; ++c) {
            f32x4 d0 = {0.f, 0.f, 0.f, 0.f};
            f32x4 d1 = {0.f, 0.f, 0.f, 0.f};
            d0 = __builtin_amdgcn_mfma_f32_16x16x32_bf16(a0, bf[c], d0, 0, 0, 0);
            d1 = __builtin_amdgcn_mfma_f32_16x16x32_bf16(a1, bf[c], d1, 0, 0, 0);
            zA[c] += esum4(d0);
            zB[c] += esum4(d1);
        }
        if (R > 0 && p >= plo && p < phi) {
#pragma unroll
            for (int s = 0; s < R; ++s) {
                f32x4 d0 = {0.f, 0.f, 0.f, 0.f};
                f32x4 d1 = {0.f, 0.f, 0.f, 0.f};
                d0 = __builtin_amdgcn_mfma_f32_16x16x32_bf16(a0, bs[s], d0, 0, 0, 0);
                d1 = __builtin_amdgcn_mfma_f32_16x16x32_bf16(a1, bs[s], d1, 0, 0, 0);
                sA[s] += esum4(d0);
                sB[s] += esum4(d1);
            }
        }
    }
    if (nt & 1) {
        bf16x8 a0 = *(const bf16x8*)(ap);
#pragma unroll
        for (int c = 0; c < NC; ++c) {
            f32x4 d0 = {0.f, 0.f, 0.f, 0.f};
            d0 = __builtin_amdgcn_mfma_f32_16x16x32_bf16(a0, bf[c], d0, 0, 0, 0);
            zA[c] += esum4(d0);
        }
        if (R > 0 && NPf >= plo && NPf < phi) {
#pragma unroll
            for (int s = 0; s < R; ++s) {
                f32x4 d0 = {0.f, 0.f, 0.f, 0.f};
                d0 = __builtin_amdgcn_mfma_f32_16x16x32_bf16(a0, bs[s], d0, 0, 0, 0);
                sA[s] += esum4(d0);
            }
        }
    }
#pragma unroll
    for (int c = 0; c < NC; ++c) {
        float z = zA[c] + zB[c];
        z += __shfl_xor(z, 16);
        z += __shfl_xor(z, 32);
        if (lane < 16) {
            int q = (c0 + c) * 16 + lane;
            Zs[q] = (q < cnt) ? 1.f / fmaxf(z - pad, 1e-9f) : 0.f;
        }
    }
    if (R > 0) {
#pragma unroll
        for (int s = 0; s < R; ++s) {
            float z = sA[s] + sB[s];
            z += __shfl_xor(z, 16);
            z += __shfl_xor(z, 32);
            if (lane < 16) atomicAdd(&Zs[(nt - R + s) * 16 + lane], z);
        }
    }
}

// ---- pass 2: w_k = sum_q exp(s_qk) * invZ_q; same ownership scheme ----
template <int NC, int R>
__device__ __forceinline__ void pass2_t(const unsigned short* __restrict__ myrow,
                                        const float* __restrict__ Zs,
                                        float* __restrict__ ws,
                                        int c0, int nt, int lane, int grp, int wv) {
    bf16x8 bf[NC];
#pragma unroll
    for (int c = 0; c < NC; ++c)
        bf[c] = *(const bf16x8*)(myrow + (size_t)(c0 + c) * 16 * RS);
    bf16x8 bs[R > 0 ? R : 1];
    float sA[R > 0 ? R : 1], sB[R > 0 ? R : 1];
    if (R > 0) {
#pragma unroll
        for (int s = 0; s < R; ++s) {
            bs[s] = *(const bf16x8*)(myrow + (size_t)(nt - R + s) * 16 * RS);
            sA[s] = 0.f; sB[s] = 0.f;
        }
    }
    float wA[NC], wB[NC];
#pragma unroll
    for (int c = 0; c < NC; ++c) { wA[c] = 0.f; wB[c] = 0.f; }
    const int NPf = nt >> 1;
    const int NP = NPf + (nt & 1);
    const int plo = (wv * NP) >> 3, phi = ((wv + 1) * NP) >> 3;
    const unsigned short* ap = myrow;
    const float* zp = Zs + grp * 4;
    for (int p = 0; p < NPf; ++p) {
        bf16x8 a0 = *(const bf16x8*)(ap);
        bf16x8 a1 = *(const bf16x8*)(ap + 16 * RS);
        ap += 32 * RS;
        float4 z0 = *(const float4*)(zp);
        float4 z1 = *(const float4*)(zp + 16);
        zp += 32;
#pragma unroll
        for (int c = 0; c < NC; ++c) {
            f32x4 d0 = {0.f, 0.f, 0.f, 0.f};
            f32x4 d1 = {0.f, 0.f, 0.f, 0.f};
            d0 = __builtin_amdgcn_mfma_f32_16x16x32_bf16(a0, bf[c], d0, 0, 0, 0);
            d1 = __builtin_amdgcn_mfma_f32_16x16x32_bf16(a1, bf[c], d1, 0, 0, 0);
            wA[c] = wsum4(d0, z0, wA[c]);
            wB[c] = wsum4(d1, z1, wB[c]);
        }
        if (R > 0 && p >= plo && p < phi) {
#pragma unroll
            for (int s = 0; s < R; ++s) {
                f32x4 d0 = {0.f, 0.f, 0.f, 0.f};
                f32x4 d1 = {0.f, 0.f, 0.f, 0.f};
                d0 = __builtin_amdgcn_mfma_f32_16x16x32_bf16(a0, bs[s], d0, 0, 0, 0);
                d1 = __builtin_amdgcn_mfma_f32_16x16x32_bf16(a1, bs[s], d1, 0, 0, 0);
                sA[s] = wsum4(d0, z0, sA[s]);
                sB[s] = wsum4(d1, z1, sB[s]);
            }
        }
    }
    if (nt & 1) {
        bf16x8 a0 = *(const bf16x8*)(ap);
        float4 z0 = *(const float4*)(zp);
#pragma unroll
        for (int c = 0; c < NC; ++c) {
            f32x4 d0 = {0.f, 0.f, 0.f, 0.f};
            d0 = __builtin_amdgcn_mfma_f32_16x16x32_bf16(a0, bf[c], d0, 0, 0, 0);
            wA[c] = wsum4(d0, z0, wA[c]);
        }
        if (R > 0 && NPf >= plo && NPf < phi) {
#pragma unroll
            for (int s = 0; s < R; ++s) {
                f32x4 d0 = {0.f, 0.f, 0.f, 0.f};
                d0 = __builtin_amdgcn_mfma_f32_16x16x32_bf16(a0, bs[s], d0, 0, 0, 0);
                sA[s] = wsum4(d0, z0, sA[s]);
            }
        }
    }
#pragma unroll
    for (int c = 0; c < NC; ++c) {
        float w = wA[c] + wB[c];
        w += __shfl_xor(w, 16);
        w += __shfl_xor(w, 32);
        if (lane < 16) ws[(c0 + c) * 16 + lane] = w;
    }
    if (R > 0) {
#pragma unroll
        for (int s = 0; s < R; ++s) {
            float w = sA[s] + sB[s];
            w += __shfl_xor(w, 16);
            w += __shfl_xor(w, 32);
            if (lane < 16) atomicAdd(&ws[(nt - R + s) * 16 + lane], w);
        }
    }
}

// block=512 (8 waves); LDS ~40.0 KB -> 4 blocks/CU = 32 waves/CU (wave cap); VGPR cap 64
extern "C" __global__ void __launch_bounds__(512, 8)
model_kernel(const float* __restrict__ X, const float* __restrict__ Xi,
             const float* __restrict__ I, const float* __restrict__ S,
             const float* __restrict__ xi_w, const float* __restrict__ xi_b,
             const float* __restrict__ xs_w, const float* __restrict__ xs_b,
             float* __restrict__ out) {
    const int n = blockIdx.x;
    const int tid = threadIdx.x;
    const int lane = tid & 63;
    const int wv = tid >> 6;          // 8 waves per block
    const int l15 = lane & 15;
    const int grp = lane >> 4;

    __shared__ __align__(16) unsigned short fxb[FCAP * RS];  // 33280 B bf16 (scaled FX)
    __shared__ unsigned short lst[FF];                       // 1024 B
    __shared__ __align__(16) float Zs[FCAP];                 // 1664 B (invZ after pass 1)
    __shared__ float ws[FCAP];                               // 1664 B
    __shared__ __align__(16) float idxb[EE];
    __shared__ float pf[16][EE];                             // 2048 B
    __shared__ float fxs_sh[EE];
    __shared__ int sh_idx;
    __shared__ int wbase[8];

    const float* Srow = S + (size_t)n * FF;
    const float* Irow = I + (size_t)n * FF;
    const float* Xrow = X + (size_t)n * FF;

    // one-hot scan + activity (512 threads == FF)
    if (Irow[tid] > 0.5f) sh_idx = tid;
    bool act = Srow[tid] > 0.f;
    unsigned long long m = __ballot(act);
    int nb = __popcll(m & ((1ull << lane) - 1ull));
    if (lane == 0) wbase[wv] = __popcll(m);
    __syncthreads();

    int off = 0;
    for (int i = 0; i < wv; ++i) off += wbase[i];
    if (act) lst[off + nb] = (unsigned short)tid;   // order-preserving compaction
    int cntr = 0;
#pragma unroll
    for (int i = 0; i < 8; ++i) cntr += wbase[i];
    const int cnt = (cntr < FCAP) ? cntr : FCAP;     // defensive cap (never triggers)
    int nt0 = (cnt + 15) >> 4;
    const int nt = (nt0 < NTCAP) ? nt0 : NTCAP;      // 16x16 tiles per side
    const int ntp16 = nt * 16;
    const int jend = ((nt + 1) >> 1) * 32;           // staged rows padded to i-unroll pair
    const int idx = sh_idx;
    if (tid < EE) idxb[tid] = xs_b[idx * EE + tid];

    // remainder-shared scheme for nt=17/18 (58% of rows); else uneven fallback
    const int r = (nt == 17) ? 1 : (nt == 18) ? 2 : 0;
    if (r > 0 && tid < r * 16) {               // pre-zero shared-col accumulators
        int sq = (nt - r) * 16 + tid;
        Zs[sq] = 0.f;
        ws[sq] = 0.f;
    }
    __syncthreads();

    // ---- build scaled FX (compacted, bf16) into LDS; zero-pad to pair boundary ----
    for (int jb = 0; jb < jend; jb += 64) {
        int j = jb + (tid >> 3);
        int e4 = (tid & 7) * 4;
        if (j < jend) {
            unsigned short h0 = 0, h1 = 0, h2 = 0, h3 = 0;
            if (j < cnt) {
                int f = lst[j];
                float xv = Xrow[f];
                float4 w4 = *(const float4*)(xs_w + f * EE + e4);
                float4 b4 = *(const float4*)(xs_b + f * EE + e4);
                float4 i4 = *(const float4*)(idxb + e4);
                h0 = f2bf(SFOLD * fmaf(xv, w4.x, b4.x + i4.x));
                h1 = f2bf(SFOLD * fmaf(xv, w4.y, b4.y + i4.y));
                h2 = f2bf(SFOLD * fmaf(xv, w4.z, b4.z + i4.z));
                h3 = f2bf(SFOLD * fmaf(xv, w4.w, b4.w + i4.w));
            }
            ushort4 pk = make_ushort4(h0, h1, h2, h3);
            *(ushort4*)(fxb + j * RS + e4) = pk;
        }
    }
    __syncthreads();

    const unsigned short* myrow = fxb + (size_t)l15 * RS + grp * 8;
    const float pad = (float)(ntp16 - cnt);

    // ownership
    int ncols, c0;
    if (r > 0) {
        ncols = 2; c0 = wv * 2;                 // 16 main cols + r shared
    } else {                                     // uneven fallback
        const int cbase = nt >> 3, crem = nt & 7;
        ncols = cbase + (wv < crem ? 1 : 0);
        c0 = wv * cbase + (wv < crem ? wv : crem);
    }

    // ---- pass 1 ----
    if (r == 1)      pass1_t<2, 1>(myrow, Zs, c0, nt, cnt, pad, lane, wv);
    else if (r == 2) pass1_t<2, 2>(myrow, Zs, c0, nt, cnt, pad, lane, wv);
    else switch (ncols) {
        case 1: pass1_t<1, 0>(myrow, Zs, c0, nt, cnt, pad, lane, wv); break;
        case 2: pass1_t<2, 0>(myrow, Zs, c0, nt, cnt, pad, lane, wv); break;
        case 3: pass1_t<3, 0>(myrow, Zs, c0, nt, cnt, pad, lane, wv); break;
        case 4: pass1_t<4, 0>(myrow, Zs, c0, nt, cnt, pad, lane, wv); break;
        default: break;
    }
    __syncthreads();
    if (r > 0 && tid < r * 16) {   // pad-correct + rcp for shared cols
        int q = (nt - r) * 16 + tid;
        Zs[q] = (q < cnt) ? 1.f / fmaxf(Zs[q] - pad, 1e-9f) : 0.f;
    }
    __syncthreads();

    // ---- pass 2 ----
    if (r == 1)      pass2_t<2, 1>(myrow, Zs, ws, c0, nt, lane, grp, wv);
    else if (r == 2) pass2_t<2, 2>(myrow, Zs, ws, c0, nt, lane, grp, wv);
    else switch (ncols) {
        case 1: pass2_t<1, 0>(myrow, Zs, ws, c0, nt, lane, grp, wv); break;
        case 2: pass2_t<2, 0>(myrow, Zs, ws, c0, nt, lane, grp, wv); break;
        case 3: pass2_t<3, 0>(myrow, Zs, ws, c0, nt, lane, grp, wv); break;
        case 4: pass2_t<4, 0>(myrow, Zs, ws, c0, nt, lane, grp, wv); break;
        default: break;
    }
    __syncthreads();

    // ---- Fxs[e] = (sum_k w_k * FX[k][e]) / cnt ; unscale by 1/SFOLD ----
    {
        int e = tid & 31, g = tid >> 5;  // 16 groups
        float acc = 0.f;
        for (int k = g; k < cnt; k += 16)
            acc += ws[k] * bf2f(fxb[k * RS + e]);
        pf[g][e] = acc;
    }
    __syncthreads();
    if (tid < EE) {
        float s = 0.f;
#pragma unroll
        for (int g = 0; g < 16; ++g) s += pf[g][tid];
        fxs_sh[tid] = s * (1.0f / SFOLD) / (float)cnt;
    }
    __syncthreads();
    if (tid < EE) {
        float fv = fxs_sh[tid];
        pf[0][tid] = xi_w[idx * EE + tid] * fv;
    }
    __syncthreads();
    if (tid == 0) {
        float a = 0.f;
#pragma unroll
        for (int e = 0; e < EE; ++e) a += pf[0][e];
        float xiv = Xi[n];
        float mm = fmaxf(a, 0.f);
        float sp = mm + logf(__expf(a - mm) + __expf(-mm));
        out[n] = xiv * a - sp;  // xi*a - softplus(a); b-terms cancel
    }
}

extern "C" void kernel_launch(void* const* d_in, const int* in_sizes, int n_in,
                              void* d_out, int out_size, void* d_ws, size_t ws_size,
                              hipStream_t stream) {
    const float* X    = (const float*)d_in[0];
    const float* Xi   = (const float*)d_in[1];
    const float* I    = (const float*)d_in[2];
    const float* S    = (const float*)d_in[3];
    const float* xi_w = (const float*)d_in[4];
    const float* xi_b = (const float*)d_in[5];
    const float* xs_w = (const float*)d_in[6];
    const float* xs_b = (const float*)d_in[7];
    float* out = (float*)d_out;
    const int N = in_sizes[1];  // Xi is [N]
    hipLaunchKernelGGL(model_kernel, dim3(N), dim3(512), 0, stream,
                       X, Xi, I, S, xi_w, xi_b, xs_w, xs_b, out);
}

// Round 11
// 117.614 us; speedup vs baseline: 2.8677x; 2.8677x over previous
//
#include <hip/hip_runtime.h>
#include <math.h>

#define FF 512
#define EE 32
#define RS 40     // LDS row stride in bf16 elements (80 B: 2-way bank alias = free)
#define FCAP 416  // staged-row cap; cnt = 1+Binom(511,0.5), max over fixed inputs ~300
#define NTCAP 26  // FCAP/16

typedef __attribute__((ext_vector_type(8))) short bf16x8;
typedef __attribute__((ext_vector_type(4))) float f32x4;

// sqrt(1/sqrt(32) * log2(e)) — folded into staged FX so MFMA output is the exp2 arg
#define SFOLD 0.5050092f

__device__ __forceinline__ unsigned short f2bf(float x) {
    unsigned int u = __float_as_uint(x);
    return (unsigned short)((u + 0x7fffu + ((u >> 16) & 1u)) >> 16);
}
__device__ __forceinline__ float bf2f(unsigned short h) {
    return __uint_as_float(((unsigned int)h) << 16);
}
__device__ __forceinline__ float esum4(f32x4 d) {
    return (__builtin_amdgcn_exp2f(d[0]) + __builtin_amdgcn_exp2f(d[1])) +
           (__builtin_amdgcn_exp2f(d[2]) + __builtin_amdgcn_exp2f(d[3]));
}
__device__ __forceinline__ float wsum4(f32x4 d, float4 z, float acc) {
    acc = fmaf(__builtin_amdgcn_exp2f(d[0]), z.x, acc);
    acc = fmaf(__builtin_amdgcn_exp2f(d[1]), z.y, acc);
    acc = fmaf(__builtin_amdgcn_exp2f(d[2]), z.z, acc);
    acc = fmaf(__builtin_amdgcn_exp2f(d[3]), z.w, acc);
    return acc;
}

// ---- pass 1 over NC contiguous column blocks owned exclusively by this wave ----
template <int NC>
__device__ __forceinline__ void pass1_cols(const unsigned short* __restrict__ myrow,
                                           float* __restrict__ Zs,
                                           int c0, int nt, int cnt, float pad, int lane) {
    bf16x8 bf[NC];
#pragma unroll
    for (int c = 0; c < NC; ++c)
        bf[c] = *(const bf16x8*)(myrow + (size_t)(c0 + c) * 16 * RS);
    float zA[NC], zB[NC];
#pragma unroll
    for (int c = 0; c < NC; ++c) { zA[c] = 0.f; zB[c] = 0.f; }
    const unsigned short* ap = myrow;
    int i = 0;
    for (; i + 2 <= nt; i += 2) {
        bf16x8 a0 = *(const bf16x8*)(ap);
        bf16x8 a1 = *(const bf16x8*)(ap + 16 * RS);
        ap += 32 * RS;
#pragma unroll
        for (int c = 0; c < NC; ++c) {
            f32x4 d0 = {0.f, 0.f, 0.f, 0.f};
            f32x4 d1 = {0.f, 0.f, 0.f, 0.f};
            d0 = __builtin_amdgcn_mfma_f32_16x16x32_bf16(a0, bf[c], d0, 0, 0, 0);
            d1 = __builtin_amdgcn_mfma_f32_16x16x32_bf16(a1, bf[c], d1, 0, 0, 0);
            zA[c] += esum4(d0);
            zB[c] += esum4(d1);
        }
    }
    if (i < nt) {
        bf16x8 a0 = *(const bf16x8*)(ap);
#pragma unroll
        for (int c = 0; c < NC; ++c) {
            f32x4 d0 = {0.f, 0.f, 0.f, 0.f};
            d0 = __builtin_amdgcn_mfma_f32_16x16x32_bf16(a0, bf[c], d0, 0, 0, 0);
            zA[c] += esum4(d0);
        }
    }
#pragma unroll
    for (int c = 0; c < NC; ++c) {
        float z = zA[c] + zB[c];
        z += __shfl_xor(z, 16);
        z += __shfl_xor(z, 32);
        if (lane < 16) {
            int q = (c0 + c) * 16 + lane;
            Zs[q] = (q < cnt) ? 1.f / fmaxf(z - pad, 1e-9f) : 0.f;
        }
    }
}

// ---- pass 2: w_k = sum_q exp(s_qk) * invZ_q over this wave's columns ----
template <int NC>
__device__ __forceinline__ void pass2_cols(const unsigned short* __restrict__ myrow,
                                           const float* __restrict__ Zs,
                                           float* __restrict__ ws,
                                           int c0, int nt, int lane, int grp) {
    bf16x8 bf[NC];
#pragma unroll
    for (int c = 0; c < NC; ++c)
        bf[c] = *(const bf16x8*)(myrow + (size_t)(c0 + c) * 16 * RS);
    float wA[NC], wB[NC];
#pragma unroll
    for (int c = 0; c < NC; ++c) { wA[c] = 0.f; wB[c] = 0.f; }
    const unsigned short* ap = myrow;
    const float* zp = Zs + grp * 4;
    int i = 0;
    for (; i + 2 <= nt; i += 2) {
        bf16x8 a0 = *(const bf16x8*)(ap);
        bf16x8 a1 = *(const bf16x8*)(ap + 16 * RS);
        ap += 32 * RS;
        float4 z0 = *(const float4*)(zp);
        float4 z1 = *(const float4*)(zp + 16);
        zp += 32;
#pragma unroll
        for (int c = 0; c < NC; ++c) {
            f32x4 d0 = {0.f, 0.f, 0.f, 0.f};
            f32x4 d1 = {0.f, 0.f, 0.f, 0.f};
            d0 = __builtin_amdgcn_mfma_f32_16x16x32_bf16(a0, bf[c], d0, 0, 0, 0);
            d1 = __builtin_amdgcn_mfma_f32_16x16x32_bf16(a1, bf[c], d1, 0, 0, 0);
            wA[c] = wsum4(d0, z0, wA[c]);
            wB[c] = wsum4(d1, z1, wB[c]);
        }
    }
    if (i < nt) {
        bf16x8 a0 = *(const bf16x8*)(ap);
        float4 z0 = *(const float4*)(zp);
#pragma unroll
        for (int c = 0; c < NC; ++c) {
            f32x4 d0 = {0.f, 0.f, 0.f, 0.f};
            d0 = __builtin_amdgcn_mfma_f32_16x16x32_bf16(a0, bf[c], d0, 0, 0, 0);
            wA[c] = wsum4(d0, z0, wA[c]);
        }
    }
#pragma unroll
    for (int c = 0; c < NC; ++c) {
        float w = wA[c] + wB[c];
        w += __shfl_xor(w, 16);
        w += __shfl_xor(w, 32);
        if (lane < 16) ws[(c0 + c) * 16 + lane] = w;
    }
}

// block=512 (8 waves); LDS ~40.0 KB -> 4 blocks/CU = 32 waves/CU (wave cap); VGPR cap 64
extern "C" __global__ void __launch_bounds__(512, 8)
model_kernel(const float* __restrict__ X, const float* __restrict__ Xi,
             const float* __restrict__ I, const float* __restrict__ S,
             const float* __restrict__ xi_w, const float* __restrict__ xi_b,
             const float* __restrict__ xs_w, const float* __restrict__ xs_b,
             float* __restrict__ out) {
    const int n = blockIdx.x;
    const int tid = threadIdx.x;
    const int lane = tid & 63;
    const int wv = tid >> 6;          // 8 waves per block
    const int l15 = lane & 15;
    const int grp = lane >> 4;

    __shared__ __align__(16) unsigned short fxb[FCAP * RS];  // 33280 B bf16 (scaled FX)
    __shared__ unsigned short lst[FF];                       // 1024 B
    __shared__ __align__(16) float Zs[FCAP];                 // 1664 B (invZ after pass 1)
    __shared__ float ws[FCAP];                               // 1664 B
    __shared__ __align__(16) float idxb[EE];
    __shared__ float pf[16][EE];                             // 2048 B
    __shared__ float fxs_sh[EE];
    __shared__ int sh_idx;
    __shared__ int wbase[8];

    const float* Srow = S + (size_t)n * FF;
    const float* Irow = I + (size_t)n * FF;
    const float* Xrow = X + (size_t)n * FF;

    // one-hot scan + activity (512 threads == FF)
    if (Irow[tid] > 0.5f) sh_idx = tid;
    bool act = Srow[tid] > 0.f;
    unsigned long long m = __ballot(act);
    int nb = __popcll(m & ((1ull << lane) - 1ull));
    if (lane == 0) wbase[wv] = __popcll(m);
    __syncthreads();

    int off = 0;
    for (int i = 0; i < wv; ++i) off += wbase[i];
    if (act) lst[off + nb] = (unsigned short)tid;   // order-preserving compaction
    int cntr = 0;
#pragma unroll
    for (int i = 0; i < 8; ++i) cntr += wbase[i];
    const int cnt = (cntr < FCAP) ? cntr : FCAP;     // defensive cap (never triggers)
    int nt0 = (cnt + 15) >> 4;
    const int nt = (nt0 < NTCAP) ? nt0 : NTCAP;      // 16x16 tiles per side
    const int ntp16 = nt * 16;
    const int jend = ((nt + 1) >> 1) * 32;           // staged rows padded to i-unroll pair
    const int idx = sh_idx;
    if (tid < EE) idxb[tid] = xs_b[idx * EE + tid];

    // remainder-shared scheme for nt=17/18 (~58% of rows); else uneven fallback
    const int r = (nt == 17 || nt == 18) ? (nt - 16) : 0;
    if (r > 0 && tid < r * 16) {               // pre-zero shared-col accumulators
        int sq = 256 + tid;                    // shared cols start at block 16
        Zs[sq] = 0.f;
        ws[sq] = 0.f;
    }
    __syncthreads();

    // ---- build scaled FX (compacted, bf16) into LDS; zero-pad to pair boundary ----
    for (int jb = 0; jb < jend; jb += 64) {
        int j = jb + (tid >> 3);
        int e4 = (tid & 7) * 4;
        if (j < jend) {
            unsigned short h0 = 0, h1 = 0, h2 = 0, h3 = 0;
            if (j < cnt) {
                int f = lst[j];
                float xv = Xrow[f];
                float4 w4 = *(const float4*)(xs_w + f * EE + e4);
                float4 b4 = *(const float4*)(xs_b + f * EE + e4);
                float4 i4 = *(const float4*)(idxb + e4);
                h0 = f2bf(SFOLD * fmaf(xv, w4.x, b4.x + i4.x));
                h1 = f2bf(SFOLD * fmaf(xv, w4.y, b4.y + i4.y));
                h2 = f2bf(SFOLD * fmaf(xv, w4.z, b4.z + i4.z));
                h3 = f2bf(SFOLD * fmaf(xv, w4.w, b4.w + i4.w));
            }
            ushort4 pk = make_ushort4(h0, h1, h2, h3);
            *(ushort4*)(fxb + j * RS + e4) = pk;
        }
    }
    __syncthreads();

    const unsigned short* myrow = fxb + (size_t)l15 * RS + grp * 8;
    const float pad = (float)(ntp16 - cnt);

    // ownership: r>0 -> each wave owns exactly 2 of the first 16 cols (balanced);
    // shared cols 16..nt-1 are split across waves by i-chunk in a separate epilogue.
    int ncols, c0;
    if (r > 0) { ncols = 2; c0 = wv * 2; }
    else {
        const int cbase = nt >> 3, crem = nt & 7;
        ncols = cbase + (wv < crem ? 1 : 0);
        c0 = wv * cbase + (wv < crem ? wv : crem);
    }

    // i-chunk split for shared-column epilogues (pair-granular)
    const int NPf = nt >> 1;
    const int NP = NPf + (nt & 1);
    const int plo = (wv * NP) >> 3, phi = ((wv + 1) * NP) >> 3;

    // ---- pass 1: Z as column sums (score matrix symmetric => col sum == row sum)
    switch (ncols) {
        case 1: pass1_cols<1>(myrow, Zs, c0, nt, cnt, pad, lane); break;
        case 2: pass1_cols<2>(myrow, Zs, c0, nt, cnt, pad, lane); break;
        case 3: pass1_cols<3>(myrow, Zs, c0, nt, cnt, pad, lane); break;
        case 4: pass1_cols<4>(myrow, Zs, c0, nt, cnt, pad, lane); break;
        default: break;
    }
    if (r > 0) {   // epilogue: shared columns, this wave's i-chunk (fresh A reads)
#pragma unroll
        for (int s = 0; s < 2; ++s) {
            if (s >= r) break;
            bf16x8 bcol = *(const bf16x8*)(myrow + (size_t)(16 + s) * 16 * RS);
            float accA = 0.f, accB = 0.f;
            for (int p = plo; p < phi; ++p) {
                const unsigned short* ap = myrow + (size_t)p * 32 * RS;
                bf16x8 a0 = *(const bf16x8*)(ap);
                f32x4 d0 = {0.f, 0.f, 0.f, 0.f};
                d0 = __builtin_amdgcn_mfma_f32_16x16x32_bf16(a0, bcol, d0, 0, 0, 0);
                accA += esum4(d0);
                if (p < NPf) {
                    bf16x8 a1 = *(const bf16x8*)(ap + 16 * RS);
                    f32x4 d1 = {0.f, 0.f, 0.f, 0.f};
                    d1 = __builtin_amdgcn_mfma_f32_16x16x32_bf16(a1, bcol, d1, 0, 0, 0);
                    accB += esum4(d1);
                }
            }
            float z = accA + accB;
            z += __shfl_xor(z, 16);
            z += __shfl_xor(z, 32);
            if (lane < 16) atomicAdd(&Zs[(16 + s) * 16 + lane], z);
        }
    }
    __syncthreads();
    if (r > 0 && tid < r * 16) {   // pad-correct + rcp for shared cols
        int q = 256 + tid;
        Zs[q] = (q < cnt) ? 1.f / fmaxf(Zs[q] - pad, 1e-9f) : 0.f;
    }
    __syncthreads();

    // ---- pass 2: w_k = sum_q exp(s_qk) * invZ_q (weighted col sums; invZ=0 masks)
    switch (ncols) {
        case 1: pass2_cols<1>(myrow, Zs, ws, c0, nt, lane, grp); break;
        case 2: pass2_cols<2>(myrow, Zs, ws, c0, nt, lane, grp); break;
        case 3: pass2_cols<3>(myrow, Zs, ws, c0, nt, lane, grp); break;
        case 4: pass2_cols<4>(myrow, Zs, ws, c0, nt, lane, grp); break;
        default: break;
    }
    if (r > 0) {   // epilogue: shared columns, this wave's i-chunk
#pragma unroll
        for (int s = 0; s < 2; ++s) {
            if (s >= r) break;
            bf16x8 bcol = *(const bf16x8*)(myrow + (size_t)(16 + s) * 16 * RS);
            float accA = 0.f, accB = 0.f;
            for (int p = plo; p < phi; ++p) {
                const unsigned short* ap = myrow + (size_t)p * 32 * RS;
                const float* zp = Zs + p * 32 + grp * 4;
                bf16x8 a0 = *(const bf16x8*)(ap);
                float4 z0 = *(const float4*)(zp);
                f32x4 d0 = {0.f, 0.f, 0.f, 0.f};
                d0 = __builtin_amdgcn_mfma_f32_16x16x32_bf16(a0, bcol, d0, 0, 0, 0);
                accA = wsum4(d0, z0, accA);
                if (p < NPf) {
                    bf16x8 a1 = *(const bf16x8*)(ap + 16 * RS);
                    float4 z1 = *(const float4*)(zp + 16);
                    f32x4 d1 = {0.f, 0.f, 0.f, 0.f};
                    d1 = __builtin_amdgcn_mfma_f32_16x16x32_bf16(a1, bcol, d1, 0, 0, 0);
                    accB = wsum4(d1, z1, accB);
                }
            }
            float w = accA + accB;
            w += __shfl_xor(w, 16);
            w += __shfl_xor(w, 32);
            if (lane < 16) atomicAdd(&ws[(16 + s) * 16 + lane], w);
        }
    }
    __syncthreads();

    // ---- Fxs[e] = (sum_k w_k * FX[k][e]) / cnt ; unscale by 1/SFOLD ----
    {
        int e = tid & 31, g = tid >> 5;  // 16 groups
        float acc = 0.f;
        for (int k = g; k < cnt; k += 16)
            acc += ws[k] * bf2f(fxb[k * RS + e]);
        pf[g][e] = acc;
    }
    __syncthreads();
    if (tid < EE) {
        float s = 0.f;
#pragma unroll
        for (int g = 0; g < 16; ++g) s += pf[g][tid];
        fxs_sh[tid] = s * (1.0f / SFOLD) / (float)cnt;
    }
    __syncthreads();
    if (tid < EE) {
        float fv = fxs_sh[tid];
        pf[0][tid] = xi_w[idx * EE + tid] * fv;
    }
    __syncthreads();
    if (tid == 0) {
        float a = 0.f;
#pragma unroll
        for (int e = 0; e < EE; ++e) a += pf[0][e];
        float xiv = Xi[n];
        float mm = fmaxf(a, 0.f);
        float sp = mm + logf(__expf(a - mm) + __expf(-mm));
        out[n] = xiv * a - sp;  // xi*a - softplus(a); b-terms cancel
    }
}

extern "C" void kernel_launch(void* const* d_in, const int* in_sizes, int n_in,
                              void* d_out, int out_size, void* d_ws, size_t ws_size,
                              hipStream_t stream) {
    const float* X    = (const float*)d_in[0];
    const float* Xi   = (const float*)d_in[1];
    const float* I    = (const float*)d_in[2];
    const float* S    = (const float*)d_in[3];
    const float* xi_w = (const float*)d_in[4];
    const float* xi_b = (const float*)d_in[5];
    const float* xs_w = (const float*)d_in[6];
    const float* xs_b = (const float*)d_in[7];
    float* out = (float*)d_out;
    const int N = in_sizes[1];  // Xi is [N]
    hipLaunchKernelGGL(model_kernel, dim3(N), dim3(512), 0, stream,
                       X, Xi, I, S, xi_w, xi_b, xs_w, xs_b, out);
}

// Round 12
// 102.365 us; speedup vs baseline: 3.2949x; 1.1490x over previous
//
#include <hip/hip_runtime.h>
#include <math.h>

#define FF 512
#define EE 32
#define RS 40     // LDS row stride in bf16 elements (80 B: 2-way bank alias = free)
#define FCAP 416  // staged-row cap; cnt = 1+Binom(511,0.5), max over fixed inputs ~300
#define NTCAP 26  // FCAP/16

typedef __attribute__((ext_vector_type(8))) short bf16x8;
typedef __attribute__((ext_vector_type(4))) float f32x4;

// sqrt(1/sqrt(32) * log2(e)) — folded into staged FX so MFMA output is the exp2 arg
#define SFOLD 0.5050092f

__device__ __forceinline__ unsigned short f2bf(float x) {
    unsigned int u = __float_as_uint(x);
    return (unsigned short)((u + 0x7fffu + ((u >> 16) & 1u)) >> 16);
}

// accumulate Z (sum of e) and h (sum of e*g) from one C/D tile fragment
__device__ __forceinline__ void zh4(f32x4 d, float4 g, float& z, float& h) {
    float e0 = __builtin_amdgcn_exp2f(d[0]);
    float e1 = __builtin_amdgcn_exp2f(d[1]);
    float e2 = __builtin_amdgcn_exp2f(d[2]);
    float e3 = __builtin_amdgcn_exp2f(d[3]);
    z += (e0 + e1) + (e2 + e3);
    h = fmaf(e0, g.x, fmaf(e1, g.y, fmaf(e2, g.z, fmaf(e3, g.w, h))));
}

// ---- fused pass over NC contiguous q-column blocks owned by this wave:
// Z_q = sum_k e_qk ; h_q = sum_k e_qk * g_k ; emit sum_q h_q/(Z_q-pad) ----
template <int NC>
__device__ __forceinline__ void fused_cols(const unsigned short* __restrict__ myrow,
                                           const float* __restrict__ gs,
                                           float* __restrict__ a_sh,
                                           int c0, int nt, int cnt, float pad,
                                           int lane, int grp) {
    bf16x8 bf[NC];
#pragma unroll
    for (int c = 0; c < NC; ++c)
        bf[c] = *(const bf16x8*)(myrow + (size_t)(c0 + c) * 16 * RS);
    float zA[NC], zB[NC], hA[NC], hB[NC];
#pragma unroll
    for (int c = 0; c < NC; ++c) { zA[c] = 0.f; zB[c] = 0.f; hA[c] = 0.f; hB[c] = 0.f; }
    const unsigned short* ap = myrow;
    const float* gp = gs + grp * 4;
    int i = 0;
    for (; i + 2 <= nt; i += 2) {
        bf16x8 a0 = *(const bf16x8*)(ap);
        bf16x8 a1 = *(const bf16x8*)(ap + 16 * RS);
        ap += 32 * RS;
        float4 g0 = *(const float4*)(gp);
        float4 g1 = *(const float4*)(gp + 16);
        gp += 32;
#pragma unroll
        for (int c = 0; c < NC; ++c) {
            f32x4 d0 = {0.f, 0.f, 0.f, 0.f};
            f32x4 d1 = {0.f, 0.f, 0.f, 0.f};
            d0 = __builtin_amdgcn_mfma_f32_16x16x32_bf16(a0, bf[c], d0, 0, 0, 0);
            d1 = __builtin_amdgcn_mfma_f32_16x16x32_bf16(a1, bf[c], d1, 0, 0, 0);
            zh4(d0, g0, zA[c], hA[c]);
            zh4(d1, g1, zB[c], hB[c]);
        }
    }
    if (i < nt) {
        bf16x8 a0 = *(const bf16x8*)(ap);
        float4 g0 = *(const float4*)(gp);
#pragma unroll
        for (int c = 0; c < NC; ++c) {
            f32x4 d0 = {0.f, 0.f, 0.f, 0.f};
            d0 = __builtin_amdgcn_mfma_f32_16x16x32_bf16(a0, bf[c], d0, 0, 0, 0);
            zh4(d0, g0, zA[c], hA[c]);
        }
    }
#pragma unroll
    for (int c = 0; c < NC; ++c) {
        float z = zA[c] + zB[c];
        float h = hA[c] + hB[c];
        z += __shfl_xor(z, 16); z += __shfl_xor(z, 32);
        h += __shfl_xor(h, 16); h += __shfl_xor(h, 32);
        int q = (c0 + c) * 16 + lane;
        float val = (lane < 16 && q < cnt) ? h / fmaxf(z - pad, 1e-9f) : 0.f;
        val += __shfl_xor(val, 1);
        val += __shfl_xor(val, 2);
        val += __shfl_xor(val, 4);
        val += __shfl_xor(val, 8);
        if (lane == 0) atomicAdd(a_sh, val);
    }
}

// block=512 (8 waves); LDS ~36.5 KB -> 4 blocks/CU = 32 waves/CU (wave cap); VGPR cap 64
extern "C" __global__ void __launch_bounds__(512, 8)
model_kernel(const float* __restrict__ X, const float* __restrict__ Xi,
             const float* __restrict__ I, const float* __restrict__ S,
             const float* __restrict__ xi_w, const float* __restrict__ xi_b,
             const float* __restrict__ xs_w, const float* __restrict__ xs_b,
             float* __restrict__ out) {
    const int n = blockIdx.x;
    const int tid = threadIdx.x;
    const int lane = tid & 63;
    const int wv = tid >> 6;          // 8 waves per block
    const int l15 = lane & 15;
    const int grp = lane >> 4;

    __shared__ __align__(16) unsigned short fxb[FCAP * RS];  // 33280 B bf16 (scaled FX)
    __shared__ unsigned short lst[FF];                       // 1024 B
    __shared__ __align__(16) float gs[FCAP];                 // 1664 B: g_k = SFOLD*FX_k.Iw
    __shared__ __align__(16) float idxb[EE];
    __shared__ __align__(16) float iw_sh[EE];
    __shared__ float a_sh;
    __shared__ int sh_idx;
    __shared__ int wbase[8];

    const float* Srow = S + (size_t)n * FF;
    const float* Irow = I + (size_t)n * FF;
    const float* Xrow = X + (size_t)n * FF;

    // one-hot scan + activity (512 threads == FF)
    if (Irow[tid] > 0.5f) sh_idx = tid;
    bool act = Srow[tid] > 0.f;
    unsigned long long m = __ballot(act);
    int nb = __popcll(m & ((1ull << lane) - 1ull));
    if (lane == 0) wbase[wv] = __popcll(m);
    __syncthreads();

    int off = 0;
    for (int i = 0; i < wv; ++i) off += wbase[i];
    if (act) lst[off + nb] = (unsigned short)tid;   // order-preserving compaction
    int cntr = 0;
#pragma unroll
    for (int i = 0; i < 8; ++i) cntr += wbase[i];
    const int cnt = (cntr < FCAP) ? cntr : FCAP;     // defensive cap (never triggers)
    int nt0 = (cnt + 15) >> 4;
    const int nt = (nt0 < NTCAP) ? nt0 : NTCAP;      // 16x16 tiles per side
    const int ntp16 = nt * 16;
    const int jend = ((nt + 1) >> 1) * 32;           // staged rows padded to i-unroll pair
    const int idx = sh_idx;
    if (tid < EE) {
        idxb[tid] = xs_b[idx * EE + tid];
        iw_sh[tid] = xi_w[idx * EE + tid];
    }
    if (tid == 0) a_sh = 0.f;
    __syncthreads();

    // ---- build scaled FX (compacted, bf16) into LDS (zero-pad to pair boundary)
    // and fused g_k = sum_e (SFOLD*FX_k[e]) * Iw[e] via 8-lane shuffle reduce ----
    for (int jb = 0; jb < jend; jb += 64) {
        int j = jb + (tid >> 3);
        int e4 = (tid & 7) * 4;
        float part = 0.f;
        if (j < jend) {
            unsigned short h0 = 0, h1 = 0, h2 = 0, h3 = 0;
            if (j < cnt) {
                int f = lst[j];
                float xv = Xrow[f];
                float4 w4 = *(const float4*)(xs_w + f * EE + e4);
                float4 b4 = *(const float4*)(xs_b + f * EE + e4);
                float4 i4 = *(const float4*)(idxb + e4);
                float r0 = SFOLD * fmaf(xv, w4.x, b4.x + i4.x);
                float r1 = SFOLD * fmaf(xv, w4.y, b4.y + i4.y);
                float r2 = SFOLD * fmaf(xv, w4.z, b4.z + i4.z);
                float r3 = SFOLD * fmaf(xv, w4.w, b4.w + i4.w);
                h0 = f2bf(r0); h1 = f2bf(r1); h2 = f2bf(r2); h3 = f2bf(r3);
                const float* iw = iw_sh + e4;
                part = fmaf(r0, iw[0], fmaf(r1, iw[1], fmaf(r2, iw[2], r3 * iw[3])));
            }
            ushort4 pk = make_ushort4(h0, h1, h2, h3);
            *(ushort4*)(fxb + j * RS + e4) = pk;
        }
        part += __shfl_xor(part, 1);
        part += __shfl_xor(part, 2);
        part += __shfl_xor(part, 4);
        if ((tid & 7) == 0 && j < jend) gs[j] = part;
    }
    __syncthreads();

    const unsigned short* myrow = fxb + (size_t)l15 * RS + grp * 8;
    const float pad = (float)(ntp16 - cnt);   // zero-padded rows add exp2(0)=1 to each Z

    // uneven contiguous column ownership (R9 scheme; TLP hides imbalance)
    const int cbase = nt >> 3, crem = nt & 7;
    const int ncols = cbase + (wv < crem ? 1 : 0);
    const int c0 = wv * cbase + (wv < crem ? wv : crem);

    // ---- single fused pass: Z_q and h_q together, one exp per pair ----
    switch (ncols) {
        case 1: fused_cols<1>(myrow, gs, &a_sh, c0, nt, cnt, pad, lane, grp); break;
        case 2: fused_cols<2>(myrow, gs, &a_sh, c0, nt, cnt, pad, lane, grp); break;
        case 3: fused_cols<3>(myrow, gs, &a_sh, c0, nt, cnt, pad, lane, grp); break;
        case 4: fused_cols<2>(myrow, gs, &a_sh, c0, nt, cnt, pad, lane, grp);
                fused_cols<2>(myrow, gs, &a_sh, c0 + 2, nt, cnt, pad, lane, grp); break;
        default: break;  // ncols == 0 (tiny cnt only)
    }
    __syncthreads();

    // ---- epilogue: a = (sum_q h_q/Z_q) / (cnt * SFOLD); out = Xi*a - softplus(a)
    if (tid == 0) {
        float a = a_sh / ((float)cnt * SFOLD);
        float xiv = Xi[n];
        float mm = fmaxf(a, 0.f);
        float sp = mm + logf(__expf(a - mm) + __expf(-mm));
        out[n] = xiv * a - sp;  // b-terms cancel
    }
}

extern "C" void kernel_launch(void* const* d_in, const int* in_sizes, int n_in,
                              void* d_out, int out_size, void* d_ws, size_t ws_size,
                              hipStream_t stream) {
    const float* X    = (const float*)d_in[0];
    const float* Xi   = (const float*)d_in[1];
    const float* I    = (const float*)d_in[2];
    const float* S    = (const float*)d_in[3];
    const float* xi_w = (const float*)d_in[4];
    const float* xi_b = (const float*)d_in[5];
    const float* xs_w = (const float*)d_in[6];
    const float* xs_b = (const float*)d_in[7];
    float* out = (float*)d_out;
    const int N = in_sizes[1];  // Xi is [N]
    hipLaunchKernelGGL(model_kernel, dim3(N), dim3(512), 0, stream,
                       X, Xi, I, S, xi_w, xi_b, xs_w, xs_b, out);
}